// Round 1
// 77.976 us; speedup vs baseline: 1.0161x; 1.0161x over previous
//
#include <hip/hip_runtime.h>

#define NB 4
#define NC 32
#define HW 4096
#define NW 64

#define PPT 2              // pixels per thread
#define TPB 256            // threads per block
#define PPB (PPT * TPB)    // 512 pixels per block
#define TILES (HW / PPB)   // 8 tiles per (b,c)

// Prep: per-center constants for the expanded quadratic form.
// arg = cf*|x|^2 + (-2 cf mu_r)*x_r + (-2 cf mu_i)*x_i + cf*|mu|^2
// rbf = exp2(arg), cf = -log2(e) / (2*sigma)
__global__ __launch_bounds__(64) void rbf_prep(
    const float* __restrict__ mu_real, const float* __restrict__ mu_imag,
    const float* __restrict__ stddev, float4* __restrict__ tab)
{
    const int k = threadIdx.x;
    if (k < NW) {
        const float mr = mu_real[k];
        const float mi = mu_imag[k];
        const float cf = -1.4426950408889634f / (2.0f * stddev[k]);
        tab[k] = make_float4(cf, -2.0f * cf * mr, -2.0f * cf * mi,
                             cf * fmaf(mr, mr, mi * mi));
    }
}

__global__ __launch_bounds__(TPB) void rbf_kernel(
    const float* __restrict__ x_real, const float* __restrict__ x_imag,
    const float* __restrict__ w_real, const float* __restrict__ w_imag,
    const float* __restrict__ b_real, const float* __restrict__ b_imag,
    const float4* __restrict__ tab, float* __restrict__ out)
{
    const int bc   = blockIdx.x / TILES;      // b*NC + c
    const int tile = blockIdx.x % TILES;
    const int c    = bc % NC;
    const int t    = threadIdx.x;

    // two adjacent pixels per thread: vectorized 8B loads / 16B store
    const int base = bc * HW + tile * PPB + 2 * t;

    const float2 vr = *reinterpret_cast<const float2*>(x_real + base);
    const float2 vi = *reinterpret_cast<const float2*>(x_imag + base);
    const float xr0 = vr.x, xr1 = vr.y;
    const float xi0 = vi.x, xi1 = vi.y;
    const float r20 = fmaf(xr0, xr0, xi0 * xi0);
    const float r21 = fmaf(xr1, xr1, xi1 * xi1);

    // bias folded into accumulator init (uniform scalar loads)
    const float br = b_real[c];
    const float bi = b_imag[c];
    float ar0 = br, ai0 = bi, ar1 = br, ai1 = bi;

    const int cbase = c * NW;   // uniform -> w reads go through scalar path

#pragma unroll 8
    for (int k = 0; k < NW; ++k) {
        const float4 cc = tab[k];              // uniform -> s_load_dwordx4
        const float  wr = w_real[cbase + k];   // uniform -> s_load
        const float  wi = w_imag[cbase + k];   // uniform -> s_load

        float t0 = fmaf(cc.z, xi0, cc.w);
        float t1 = fmaf(cc.z, xi1, cc.w);
        t0 = fmaf(cc.y, xr0, t0);
        t1 = fmaf(cc.y, xr1, t1);
        t0 = fmaf(cc.x, r20, t0);
        t1 = fmaf(cc.x, r21, t1);

        const float e0 = __builtin_amdgcn_exp2f(t0);
        const float e1 = __builtin_amdgcn_exp2f(t1);

        ar0 = fmaf(e0, wr, ar0);
        ai0 = fmaf(e0, wi, ai0);
        ar1 = fmaf(e1, wr, ar1);
        ai1 = fmaf(e1, wi, ai1);
    }

    // out layout (B,C,H,W,2): two adjacent pixels -> one float4 store
    float4* __restrict__ o4 = reinterpret_cast<float4*>(out + 2 * base);
    *o4 = make_float4(ar0, ai0, ar1, ai1);
}

extern "C" void kernel_launch(void* const* d_in, const int* in_sizes, int n_in,
                              void* d_out, int out_size, void* d_ws, size_t ws_size,
                              hipStream_t stream) {
    const float* x_real  = (const float*)d_in[0];
    const float* x_imag  = (const float*)d_in[1];
    const float* w_real  = (const float*)d_in[2];
    const float* w_imag  = (const float*)d_in[3];
    const float* b_real  = (const float*)d_in[4];
    const float* b_imag  = (const float*)d_in[5];
    const float* mu_real = (const float*)d_in[6];
    const float* mu_imag = (const float*)d_in[7];
    const float* stddev  = (const float*)d_in[8];
    float* out  = (float*)d_out;
    float4* tab = (float4*)d_ws;   // 64 * 16 B = 1 KiB of workspace

    rbf_prep<<<1, 64, 0, stream>>>(mu_real, mu_imag, stddev, tab);

    const int grid = NB * NC * TILES;  // 1024 blocks, 4 waves/SIMD
    rbf_kernel<<<grid, TPB, 0, stream>>>(x_real, x_imag, w_real, w_imag,
                                         b_real, b_imag, tab, out);
}